// Round 1
// baseline (3663.926 us; speedup 1.0000x reference)
//
#include <hip/hip_runtime.h>
#include <math.h>

#define TPB 256
#define EPSF 1e-6f
#define LOG_G1 -2.3025850929940457f   /* log(0.1) */
#define LOGEPS -13.815510557964274f   /* log(1e-6) */
#define NEG_INF_KEY 0x007FFFFFu       /* f2key(-inf) */

// order-preserving float->uint map (works for all signs)
__device__ __forceinline__ unsigned f2key(float x){
  unsigned u = __float_as_uint(x);
  return (u & 0x80000000u) ? ~u : (u | 0x80000000u);
}
__device__ __forceinline__ float key2f(unsigned k){
  return (k & 0x80000000u) ? __uint_as_float(k & 0x7fffffffu)
                           : __uint_as_float(~k);
}

// ---------------- init: per-voxel state ----------------
__global__ void k_init(unsigned* __restrict__ segmax_key, float* __restrict__ seg_sum,
                       unsigned* __restrict__ cnt, unsigned* __restrict__ maxop_key,
                       float* __restrict__ agg, int M){
  int v = blockIdx.x * TPB + threadIdx.x;
  if (v < M){
    segmax_key[v] = NEG_INF_KEY;
    seg_sum[v]    = 0.0f;
    cnt[v]        = 0u;
    maxop_key[v]  = NEG_INF_KEY;
  }
  long long total = (long long)M * 14;
  for (long long i = (long long)blockIdx.x * TPB + threadIdx.x; i < total;
       i += (long long)gridDim.x * TPB)
    agg[i] = 0.0f;
}

// ---------------- pass 1: scores + segment max ----------------
__global__ void k_score(const float* __restrict__ feat, const float* __restrict__ conf,
                        const int* __restrict__ vox, const float* __restrict__ tt,
                        float* __restrict__ score_out, unsigned* __restrict__ segmax_key,
                        int N){
  int i = blockIdx.x * TPB + threadIdx.x;
  if (i >= N) return;
  float t0     = tt[0];
  float g_time = feat[(size_t)i * 15 + 14];
  float g0     = fmaxf(conf[i], EPSF);
  float sigma  = LOG_G1 / (g0 * g0 + EPSF);
  float dt     = t0 - g_time;
  // log(max(exp(sigma*dt^2), EPS)) == max(sigma*dt^2, log(EPS)) exactly
  float s = fmaxf(sigma * dt * dt, LOGEPS) / 0.07f;
  score_out[i] = s;
  atomicMax(&segmax_key[vox[i]], f2key(s));
}

// ---------------- pass 2: ex + all segment sums/maxes ----------------
__global__ __launch_bounds__(TPB)
void k_accum(const float* __restrict__ feat, const int* __restrict__ vox,
             float* sc_ex /* in: score, out: ex (same buffer) */,
             const unsigned* __restrict__ segmax_key,
             float* __restrict__ seg_sum, unsigned* __restrict__ cnt,
             unsigned* __restrict__ maxop_key, float* __restrict__ agg, int N){
  __shared__ float sf[TPB * 15];
  int base = blockIdx.x * TPB;
  int nrow = N - base; if (nrow > TPB) nrow = TPB;
  int nflt = nrow * 15;
  if (nflt == TPB * 15){
    // fully coalesced float4 staging (15360 B per block, 16B-aligned)
    const float4* g4 = (const float4*)(feat + (size_t)base * 15);
    float4* s4 = (float4*)sf;
    #pragma unroll
    for (int k = 0; k < 4; ++k){
      int idx = threadIdx.x + k * TPB;
      if (idx < TPB * 15 / 4) s4[idx] = g4[idx];
    }
  } else {
    for (int idx = threadIdx.x; idx < nflt; idx += TPB)
      sf[idx] = feat[(size_t)base * 15 + idx];
  }
  __syncthreads();
  int t = threadIdx.x;
  if (t >= nrow) return;
  int i = base + t;
  const float* row = &sf[t * 15];       // stride 15: conflict-free (gcd(15,32)=1)
  int   v  = vox[i];
  float s  = sc_ex[i];
  float m  = key2f(segmax_key[v]);
  float ex = expf(s - m);
  sc_ex[i] = ex;                         // stash unnormalized weight
  unsafeAtomicAdd(&seg_sum[v], ex);
  atomicAdd(&cnt[v], 1u);
  atomicMax(&maxop_key[v], f2key(row[6]));
  float* a = &agg[(size_t)v * 14];
  #pragma unroll
  for (int k = 0; k < 7; ++k)  unsafeAtomicAdd(&a[k], row[k] * ex);
  #pragma unroll
  for (int k = 7; k < 10; ++k) unsafeAtomicAdd(&a[k], logf(fmaxf(row[k], 1e-6f)) * ex);
  #pragma unroll
  for (int k = 10; k < 14; ++k) unsafeAtomicAdd(&a[k], row[k] * ex);
}

// ---------------- pass 3: normalize weights ----------------
__global__ void k_norm(const int* __restrict__ vox, const float* __restrict__ seg_sum,
                       float* __restrict__ w, int N){
  int i = blockIdx.x * TPB + threadIdx.x;
  if (i >= N) return;
  w[i] = w[i] / seg_sum[vox[i]];
}

// ---------------- pass 4: per-voxel finalize ----------------
__global__ void k_final(const float* __restrict__ seg_sum, const unsigned* __restrict__ cnt,
                        const unsigned* __restrict__ maxop_key, const float* __restrict__ agg,
                        float* __restrict__ F, int M){
  int v = blockIdx.x * TPB + threadIdx.x;
  if (v >= M) return;
  unsigned c = cnt[v];
  float inv  = (c > 0u) ? 1.0f / seg_sum[v] : 0.0f;
  float a[14];
  const float* ap = &agg[(size_t)v * 14];
  #pragma unroll
  for (int k = 0; k < 14; ++k) a[k] = ap[k] * inv;   // agg(ex-weighted) / sum(ex)
  float maxop = (c > 0u) ? key2f(maxop_key[v]) : 0.0f;
  float* f = &F[(size_t)v * 15];
  f[0] = a[0]; f[1] = a[1]; f[2] = a[2];
  f[3] = a[3]; f[4] = a[4]; f[5] = a[5];
  f[6] = 0.7f * maxop + 0.3f * a[6];
  f[7] = expf(a[7]); f[8] = expf(a[8]); f[9] = expf(a[9]);
  float r0 = a[10], r1 = a[11], r2 = a[12], r3 = a[13];
  float nrm = sqrtf(r0*r0 + r1*r1 + r2*r2 + r3*r3);
  float rinv = 1.0f / fmaxf(nrm, 1e-6f);
  f[10] = r0 * rinv; f[11] = r1 * rinv; f[12] = r2 * rinv; f[13] = r3 * rinv;
  f[14] = 0.0f;
}

extern "C" void kernel_launch(void* const* d_in, const int* in_sizes, int n_in,
                              void* d_out, int out_size, void* d_ws, size_t ws_size,
                              hipStream_t stream) {
  const float* feat = (const float*)d_in[0];
  const int*   vox  = (const int*)  d_in[1];
  // d_in[2] = num_voxels (device scalar, unused — derived below)
  const float* tt   = (const float*)d_in[3];
  const float* conf = (const float*)d_in[4];

  int N = in_sizes[0] / 15;
  int M = (out_size - N) / 15;

  float* F = (float*)d_out;                     // fused gaussians: M*15
  float* W = (float*)d_out + (size_t)M * 15;    // weights: N (holds score, then ex, then w)

  unsigned* segmax_key = (unsigned*)d_ws;
  float*    seg_sum    = (float*)d_ws + M;
  unsigned* cnt        = (unsigned*)d_ws + 2 * (size_t)M;
  unsigned* maxop_key  = (unsigned*)d_ws + 3 * (size_t)M;
  float*    agg        = (float*)d_ws + 4 * (size_t)M;   // M*14

  int gM = (M + TPB - 1) / TPB;
  int gN = (N + TPB - 1) / TPB;

  k_init <<<gM, TPB, 0, stream>>>(segmax_key, seg_sum, cnt, maxop_key, agg, M);
  k_score<<<gN, TPB, 0, stream>>>(feat, conf, vox, tt, W, segmax_key, N);
  k_accum<<<gN, TPB, 0, stream>>>(feat, vox, W, segmax_key, seg_sum, cnt, maxop_key, agg, N);
  k_norm <<<gN, TPB, 0, stream>>>(vox, seg_sum, W, N);
  k_final<<<gM, TPB, 0, stream>>>(seg_sum, cnt, maxop_key, agg, F, M);
}

// Round 2
// 795.712 us; speedup vs baseline: 4.6046x; 4.6046x over previous
//
#include <hip/hip_runtime.h>
#include <math.h>

#define TPB 256
#define GRP 16                        // lanes per voxel in k_reduce
#define EPSF 1e-6f
#define LOG_G1 -2.3025850929940457f   /* log(0.1) */
#define LOGEPS -13.815510557964274f   /* log(1e-6) */

// ---- 16-lane-group butterfly reductions (4 voxels per wave64) ----
__device__ __forceinline__ float gsum16(float x){
  #pragma unroll
  for (int k = 8; k >= 1; k >>= 1) x += __shfl_xor(x, k, 64);
  return x;
}
__device__ __forceinline__ float gmax16(float x){
  #pragma unroll
  for (int k = 8; k >= 1; k >>= 1) x = fmaxf(x, __shfl_xor(x, k, 64));
  return x;
}

__device__ __forceinline__ float score_of(const float* __restrict__ feat,
                                          const float* __restrict__ conf,
                                          float t0, unsigned idx){
  float gt = feat[(size_t)idx * 15 + 14];
  float g0 = fmaxf(conf[idx], EPSF);
  float dt = t0 - gt;
  // log(max(exp(sigma*dt^2),EPS))/T == max(sigma*dt^2, logEPS)/T exactly
  return fmaxf(LOG_G1 / (g0 * g0 + EPSF) * dt * dt, LOGEPS) / 0.07f;
}

// ---------------- zero histogram ----------------
__global__ void k_zero(unsigned* __restrict__ cnt, int M){
  int v = blockIdx.x * TPB + threadIdx.x;
  if (v < M) cnt[v] = 0u;
}

// ---------------- rank assignment (the only atomics left) ----------------
__global__ void k_rank(const int* __restrict__ vox, unsigned* __restrict__ cnt,
                       unsigned* __restrict__ rank, int N){
  int i = blockIdx.x * TPB + threadIdx.x;
  if (i >= N) return;
  rank[i] = atomicAdd(&cnt[vox[i]], 1u);
}

// ---------------- scan: per-block sums ----------------
__global__ void k_scan1(const unsigned* __restrict__ cnt, unsigned* __restrict__ bsum, int M){
  __shared__ unsigned sm[TPB];
  int i = blockIdx.x * TPB + threadIdx.x;
  sm[threadIdx.x] = (i < M) ? cnt[i] : 0u;
  __syncthreads();
  for (int off = TPB / 2; off > 0; off >>= 1){
    if (threadIdx.x < off) sm[threadIdx.x] += sm[threadIdx.x + off];
    __syncthreads();
  }
  if (threadIdx.x == 0) bsum[blockIdx.x] = sm[0];
}

// ---------------- scan: exclusive scan of block sums (single block) ----------------
__global__ void k_scan2(unsigned* __restrict__ bsum, int nb){
  __shared__ unsigned sm[TPB];
  unsigned carry = 0;
  for (int base = 0; base < nb; base += TPB){
    int i = base + threadIdx.x;
    unsigned v = (i < nb) ? bsum[i] : 0u;
    sm[threadIdx.x] = v;
    __syncthreads();
    for (int off = 1; off < TPB; off <<= 1){
      unsigned t = (threadIdx.x >= off) ? sm[threadIdx.x - off] : 0u;
      __syncthreads();
      sm[threadIdx.x] += t;
      __syncthreads();
    }
    if (i < nb) bsum[i] = carry + sm[threadIdx.x] - v;   // exclusive
    carry += sm[TPB - 1];
    __syncthreads();
  }
}

// ---------------- scan: per-voxel exclusive offsets ----------------
__global__ void k_scan3(const unsigned* __restrict__ cnt, const unsigned* __restrict__ bsum,
                        unsigned* __restrict__ offs, int M){
  __shared__ unsigned sm[TPB];
  int i = blockIdx.x * TPB + threadIdx.x;
  unsigned v = (i < M) ? cnt[i] : 0u;
  sm[threadIdx.x] = v;
  __syncthreads();
  for (int off = 1; off < TPB; off <<= 1){
    unsigned t = (threadIdx.x >= off) ? sm[threadIdx.x - off] : 0u;
    __syncthreads();
    sm[threadIdx.x] += t;
    __syncthreads();
  }
  if (i < M) offs[i] = bsum[blockIdx.x] + sm[threadIdx.x] - v;
}

// ---------------- scatter indices into voxel-sorted order ----------------
__global__ void k_scatter(const int* __restrict__ vox, const unsigned* __restrict__ rank,
                          const unsigned* __restrict__ offs, unsigned* __restrict__ sidx, int N){
  int i = blockIdx.x * TPB + threadIdx.x;
  if (i >= N) return;
  sidx[offs[vox[i]] + rank[i]] = (unsigned)i;
}

// ---------------- per-voxel softmax + weighted reduction (no atomics) ----------------
__global__ __launch_bounds__(TPB)
void k_reduce(const float* __restrict__ feat, const float* __restrict__ conf,
              const float* __restrict__ tt, const unsigned* __restrict__ sidx,
              const unsigned* __restrict__ offs, const unsigned* __restrict__ cnt,
              float* __restrict__ F, float* __restrict__ W, int M){
  int v = blockIdx.x * (TPB / GRP) + (int)(threadIdx.x / GRP);
  if (v >= M) return;                       // whole 16-lane group returns together
  int sl = threadIdx.x & (GRP - 1);
  unsigned off = offs[v], L = cnt[v];
  float t0 = tt[0];

  // phase 0: segment max of scores
  float m = -INFINITY;
  for (unsigned j = sl; j < L; j += GRP)
    m = fmaxf(m, score_of(feat, conf, t0, sidx[off + j]));
  m = gmax16(m);

  // phase 1: ex + weighted sums (rows L1/L2-hot from phase 0)
  float se = 0.f, mop = -INFINITY;
  float a0=0,a1=0,a2=0,a3=0,a4=0,a5=0,a6=0,a7=0,a8=0,a9=0,a10=0,a11=0,a12=0,a13=0;
  for (unsigned j = sl; j < L; j += GRP){
    unsigned idx = sidx[off + j];
    const float* r = feat + (size_t)idx * 15;
    float s = score_of(feat, conf, t0, idx);
    float e = expf(s - m);
    se += e;
    float r6 = r[6];
    mop = fmaxf(mop, r6);
    a0  += r[0]  * e;  a1  += r[1]  * e;  a2  += r[2]  * e;
    a3  += r[3]  * e;  a4  += r[4]  * e;  a5  += r[5]  * e;
    a6  += r6    * e;
    a7  += logf(fmaxf(r[7], 1e-6f)) * e;
    a8  += logf(fmaxf(r[8], 1e-6f)) * e;
    a9  += logf(fmaxf(r[9], 1e-6f)) * e;
    a10 += r[10] * e;  a11 += r[11] * e;  a12 += r[12] * e;  a13 += r[13] * e;
  }
  se  = gsum16(se);
  a0  = gsum16(a0);  a1  = gsum16(a1);  a2  = gsum16(a2);  a3  = gsum16(a3);
  a4  = gsum16(a4);  a5  = gsum16(a5);  a6  = gsum16(a6);  a7  = gsum16(a7);
  a8  = gsum16(a8);  a9  = gsum16(a9);  a10 = gsum16(a10); a11 = gsum16(a11);
  a12 = gsum16(a12); a13 = gsum16(a13);
  mop = gmax16(mop);

  float inv = (L > 0u) ? 1.0f / se : 0.0f;

  // phase 2: per-gaussian normalized weights (scattered 4B writes)
  for (unsigned j = sl; j < L; j += GRP){
    unsigned idx = sidx[off + j];
    float s = score_of(feat, conf, t0, idx);
    W[idx] = expf(s - m) * inv;
  }

  // finalize voxel row
  if (sl == 0){
    float b0=a0*inv, b1=a1*inv, b2=a2*inv, b3=a3*inv, b4=a4*inv, b5=a5*inv, b6=a6*inv;
    float b7=a7*inv, b8=a8*inv, b9=a9*inv;
    float r0=a10*inv, r1=a11*inv, r2=a12*inv, r3=a13*inv;
    float maxop = (L > 0u) ? mop : 0.0f;
    float nrm  = sqrtf(r0*r0 + r1*r1 + r2*r2 + r3*r3);
    float rinv = 1.0f / fmaxf(nrm, 1e-6f);
    float* f = F + (size_t)v * 15;
    f[0]=b0; f[1]=b1; f[2]=b2; f[3]=b3; f[4]=b4; f[5]=b5;
    f[6]=0.7f*maxop + 0.3f*b6;
    f[7]=expf(b7); f[8]=expf(b8); f[9]=expf(b9);
    f[10]=r0*rinv; f[11]=r1*rinv; f[12]=r2*rinv; f[13]=r3*rinv;
    f[14]=0.0f;
  }
}

extern "C" void kernel_launch(void* const* d_in, const int* in_sizes, int n_in,
                              void* d_out, int out_size, void* d_ws, size_t ws_size,
                              hipStream_t stream) {
  const float* feat = (const float*)d_in[0];
  const int*   vox  = (const int*)  d_in[1];
  const float* tt   = (const float*)d_in[3];
  const float* conf = (const float*)d_in[4];

  int N = in_sizes[0] / 15;
  int M = (out_size - N) / 15;
  int nb = (M + TPB - 1) / TPB;

  float* F = (float*)d_out;                      // fused gaussians: M*15
  float* W = (float*)d_out + (size_t)M * 15;     // weights: N

  unsigned* cnt  = (unsigned*)d_ws;              // M
  unsigned* offs = cnt  + M;                     // M
  unsigned* bsum = offs + M;                     // nb
  unsigned* rank = bsum + nb;                    // N
  unsigned* sidx = rank + (size_t)N;             // N

  int gM = (M + TPB - 1) / TPB;
  int gN = (N + TPB - 1) / TPB;
  int gR = (M * GRP + TPB - 1) / TPB;            // 16 voxels per 256-thread block

  k_zero   <<<gM, TPB, 0, stream>>>(cnt, M);
  k_rank   <<<gN, TPB, 0, stream>>>(vox, cnt, rank, N);
  k_scan1  <<<nb, TPB, 0, stream>>>(cnt, bsum, M);
  k_scan2  <<<1,  TPB, 0, stream>>>(bsum, nb);
  k_scan3  <<<nb, TPB, 0, stream>>>(cnt, bsum, offs, M);
  k_scatter<<<gN, TPB, 0, stream>>>(vox, rank, offs, sidx, N);
  k_reduce <<<gR, TPB, 0, stream>>>(feat, conf, tt, sidx, offs, cnt, F, W, M);
}

// Round 3
// 622.429 us; speedup vs baseline: 5.8865x; 1.2784x over previous
//
#include <hip/hip_runtime.h>
#include <math.h>

#define TPB 256
#define GRP 16                        // lanes per voxel in reduce
#define EPSF 1e-6f
#define LOG_G1 -2.3025850929940457f   /* log(0.1) */
#define LOGEPS -13.815510557964274f   /* log(1e-6) */

// ---- 16-lane-group butterfly reductions (4 voxels per wave64) ----
__device__ __forceinline__ float gsum16(float x){
  #pragma unroll
  for (int k = 8; k >= 1; k >>= 1) x += __shfl_xor(x, k, 64);
  return x;
}
__device__ __forceinline__ float gmax16(float x){
  #pragma unroll
  for (int k = 8; k >= 1; k >>= 1) x = fmaxf(x, __shfl_xor(x, k, 64));
  return x;
}
__device__ __forceinline__ float score_from(float gt, float c, float t0){
  float g0 = fmaxf(c, EPSF);
  float dt = t0 - gt;
  // log(max(exp(sigma*dt^2),EPS))/T == max(sigma*dt^2, logEPS)/T exactly
  return fmaxf(LOG_G1 / (g0 * g0 + EPSF) * dt * dt, LOGEPS) / 0.07f;
}

// ---------------- zero counters ----------------
__global__ void k_zero(unsigned* __restrict__ p, int n){
  int i = blockIdx.x * TPB + threadIdx.x;
  if (i < n) p[i] = 0u;
}

// ---------------- histogram ----------------
__global__ void k_count(const int* __restrict__ vox, unsigned* __restrict__ cnt, int N){
  int i = blockIdx.x * TPB + threadIdx.x;
  if (i >= N) return;
  atomicAdd(&cnt[vox[i]], 1u);
}

// ---------------- scan: per-block sums ----------------
__global__ void k_scan1(const unsigned* __restrict__ cnt, unsigned* __restrict__ bsum, int M){
  __shared__ unsigned sm[TPB];
  int i = blockIdx.x * TPB + threadIdx.x;
  sm[threadIdx.x] = (i < M) ? cnt[i] : 0u;
  __syncthreads();
  for (int off = TPB / 2; off > 0; off >>= 1){
    if (threadIdx.x < off) sm[threadIdx.x] += sm[threadIdx.x + off];
    __syncthreads();
  }
  if (threadIdx.x == 0) bsum[blockIdx.x] = sm[0];
}

// ---------------- scan: exclusive scan of block sums (single block) ----------------
__global__ void k_scan2(unsigned* __restrict__ bsum, int nb){
  __shared__ unsigned sm[TPB];
  unsigned carry = 0;
  for (int base = 0; base < nb; base += TPB){
    int i = base + threadIdx.x;
    unsigned v = (i < nb) ? bsum[i] : 0u;
    sm[threadIdx.x] = v;
    __syncthreads();
    for (int off = 1; off < TPB; off <<= 1){
      unsigned t = (threadIdx.x >= off) ? sm[threadIdx.x - off] : 0u;
      __syncthreads();
      sm[threadIdx.x] += t;
      __syncthreads();
    }
    if (i < nb) bsum[i] = carry + sm[threadIdx.x] - v;   // exclusive
    carry += sm[TPB - 1];
    __syncthreads();
  }
}

// ---------------- scan: per-voxel exclusive offsets ----------------
__global__ void k_scan3(const unsigned* __restrict__ cnt, const unsigned* __restrict__ bsum,
                        unsigned* __restrict__ offs, int M){
  __shared__ unsigned sm[TPB];
  int i = blockIdx.x * TPB + threadIdx.x;
  unsigned v = (i < M) ? cnt[i] : 0u;
  sm[threadIdx.x] = v;
  __syncthreads();
  for (int off = 1; off < TPB; off <<= 1){
    unsigned t = (threadIdx.x >= off) ? sm[threadIdx.x - off] : 0u;
    __syncthreads();
    sm[threadIdx.x] += t;
    __syncthreads();
  }
  if (i < M) offs[i] = bsum[blockIdx.x] + sm[threadIdx.x] - v;
}

// ================= PLAN A: full 64B sorted payload =================
// payload row (16 floats): [f0..f6, log(max(f7..f9,1e-6)), f10..f13, score, idx]
__global__ __launch_bounds__(TPB)
void k_transformA(const float* __restrict__ feat, const float* __restrict__ conf,
                  const int* __restrict__ vox, const float* __restrict__ tt,
                  const unsigned* __restrict__ offs, unsigned* __restrict__ cnt2,
                  float* __restrict__ payload, int N){
  __shared__ float sf[TPB * 15];
  int base = blockIdx.x * TPB;
  int nrow = N - base; if (nrow > TPB) nrow = TPB;
  int nflt = nrow * 15;
  if (nflt == TPB * 15){
    const float4* g4 = (const float4*)(feat + (size_t)base * 15);
    float4* s4 = (float4*)sf;
    #pragma unroll
    for (int k = 0; k < 4; ++k){
      int idx = threadIdx.x + k * TPB;
      if (idx < TPB * 15 / 4) s4[idx] = g4[idx];
    }
  } else {
    for (int idx = threadIdx.x; idx < nflt; idx += TPB)
      sf[idx] = feat[(size_t)base * 15 + idx];
  }
  __syncthreads();
  int t = threadIdx.x;
  if (t >= nrow) return;
  int i = base + t;
  const float* r = &sf[t * 15];          // stride 15: conflict-free
  float s  = score_from(r[14], conf[i], tt[0]);
  int   v  = vox[i];
  unsigned rk = atomicAdd(&cnt2[v], 1u);
  size_t pos = (size_t)(offs[v] + rk) * 16;
  float4* p4 = (float4*)(payload + pos);
  p4[0] = make_float4(r[0], r[1], r[2], r[3]);
  p4[1] = make_float4(r[4], r[5], r[6], logf(fmaxf(r[7], 1e-6f)));
  p4[2] = make_float4(logf(fmaxf(r[8], 1e-6f)), logf(fmaxf(r[9], 1e-6f)), r[10], r[11]);
  p4[3] = make_float4(r[12], r[13], s, __uint_as_float((unsigned)i));
}

__global__ __launch_bounds__(TPB)
void k_reduceA(const float4* __restrict__ pay4, const unsigned* __restrict__ offs,
               const unsigned* __restrict__ cnt, float* __restrict__ F,
               float* __restrict__ W, int M){
  int v = blockIdx.x * (TPB / GRP) + (int)(threadIdx.x / GRP);
  if (v >= M) return;
  int sl = threadIdx.x & (GRP - 1);
  unsigned off = offs[v], L = cnt[v];

  float m = -INFINITY;
  for (unsigned j = sl; j < L; j += GRP)
    m = fmaxf(m, pay4[(size_t)(off + j) * 4 + 3].z);
  m = gmax16(m);

  float se = 0.f, mop = -INFINITY;
  float a0=0,a1=0,a2=0,a3=0,a4=0,a5=0,a6=0,a7=0,a8=0,a9=0,a10=0,a11=0,a12=0,a13=0;
  for (unsigned j = sl; j < L; j += GRP){
    size_t b = (size_t)(off + j) * 4;
    float4 q0 = pay4[b], q1 = pay4[b+1], q2 = pay4[b+2], q3 = pay4[b+3];
    float e = expf(q3.z - m);
    se += e;
    mop = fmaxf(mop, q1.z);
    a0 += q0.x*e; a1 += q0.y*e; a2  += q0.z*e; a3  += q0.w*e;
    a4 += q1.x*e; a5 += q1.y*e; a6  += q1.z*e; a7  += q1.w*e;
    a8 += q2.x*e; a9 += q2.y*e; a10 += q2.z*e; a11 += q2.w*e;
    a12 += q3.x*e; a13 += q3.y*e;
  }
  se  = gsum16(se);
  a0  = gsum16(a0);  a1  = gsum16(a1);  a2  = gsum16(a2);  a3  = gsum16(a3);
  a4  = gsum16(a4);  a5  = gsum16(a5);  a6  = gsum16(a6);  a7  = gsum16(a7);
  a8  = gsum16(a8);  a9  = gsum16(a9);  a10 = gsum16(a10); a11 = gsum16(a11);
  a12 = gsum16(a12); a13 = gsum16(a13);
  mop = gmax16(mop);

  float inv = (L > 0u) ? 1.0f / se : 0.0f;

  for (unsigned j = sl; j < L; j += GRP){
    float4 q3 = pay4[(size_t)(off + j) * 4 + 3];      // L1/L2-hot
    W[__float_as_uint(q3.w)] = expf(q3.z - m) * inv;
  }

  if (sl == 0){
    float b0=a0*inv, b1=a1*inv, b2=a2*inv, b3=a3*inv, b4=a4*inv, b5=a5*inv, b6=a6*inv;
    float b7=a7*inv, b8=a8*inv, b9=a9*inv;
    float r0=a10*inv, r1=a11*inv, r2=a12*inv, r3=a13*inv;
    float maxop = (L > 0u) ? mop : 0.0f;
    float nrm  = sqrtf(r0*r0 + r1*r1 + r2*r2 + r3*r3);
    float rinv = 1.0f / fmaxf(nrm, 1e-6f);
    float* f = F + (size_t)v * 15;
    f[0]=b0; f[1]=b1; f[2]=b2; f[3]=b3; f[4]=b4; f[5]=b5;
    f[6]=0.7f*maxop + 0.3f*b6;
    f[7]=expf(b7); f[8]=expf(b8); f[9]=expf(b9);
    f[10]=r0*rinv; f[11]=r1*rinv; f[12]=r2*rinv; f[13]=r3*rinv;
    f[14]=0.0f;
  }
}

// ================= PLAN B: sorted (score, idx) pairs, gather rows =================
__global__ void k_scoreB(const float* __restrict__ feat, const float* __restrict__ conf,
                         const int* __restrict__ vox, const float* __restrict__ tt,
                         const unsigned* __restrict__ offs, unsigned* __restrict__ cnt2,
                         float2* __restrict__ pairs, int N){
  int i = blockIdx.x * TPB + threadIdx.x;
  if (i >= N) return;
  float s = score_from(feat[(size_t)i * 15 + 14], conf[i], tt[0]);
  int v = vox[i];
  unsigned rk = atomicAdd(&cnt2[v], 1u);
  pairs[offs[v] + rk] = make_float2(s, __uint_as_float((unsigned)i));
}

__global__ __launch_bounds__(TPB)
void k_reduceB(const float* __restrict__ feat, const float2* __restrict__ pairs,
               const unsigned* __restrict__ offs, const unsigned* __restrict__ cnt,
               float* __restrict__ F, float* __restrict__ W, int M){
  int v = blockIdx.x * (TPB / GRP) + (int)(threadIdx.x / GRP);
  if (v >= M) return;
  int sl = threadIdx.x & (GRP - 1);
  unsigned off = offs[v], L = cnt[v];

  float m = -INFINITY;
  for (unsigned j = sl; j < L; j += GRP)
    m = fmaxf(m, pairs[off + j].x);
  m = gmax16(m);

  float se = 0.f, mop = -INFINITY;
  float a0=0,a1=0,a2=0,a3=0,a4=0,a5=0,a6=0,a7=0,a8=0,a9=0,a10=0,a11=0,a12=0,a13=0;
  for (unsigned j = sl; j < L; j += GRP){
    float2 pr = pairs[off + j];                      // L2-hot
    unsigned idx = __float_as_uint(pr.y);
    const float* r = feat + (size_t)idx * 15;
    float e = expf(pr.x - m);
    se += e;
    float r6 = r[6];
    mop = fmaxf(mop, r6);
    a0  += r[0]  * e;  a1  += r[1]  * e;  a2  += r[2]  * e;
    a3  += r[3]  * e;  a4  += r[4]  * e;  a5  += r[5]  * e;
    a6  += r6    * e;
    a7  += logf(fmaxf(r[7], 1e-6f)) * e;
    a8  += logf(fmaxf(r[8], 1e-6f)) * e;
    a9  += logf(fmaxf(r[9], 1e-6f)) * e;
    a10 += r[10] * e;  a11 += r[11] * e;  a12 += r[12] * e;  a13 += r[13] * e;
  }
  se  = gsum16(se);
  a0  = gsum16(a0);  a1  = gsum16(a1);  a2  = gsum16(a2);  a3  = gsum16(a3);
  a4  = gsum16(a4);  a5  = gsum16(a5);  a6  = gsum16(a6);  a7  = gsum16(a7);
  a8  = gsum16(a8);  a9  = gsum16(a9);  a10 = gsum16(a10); a11 = gsum16(a11);
  a12 = gsum16(a12); a13 = gsum16(a13);
  mop = gmax16(mop);

  float inv = (L > 0u) ? 1.0f / se : 0.0f;

  for (unsigned j = sl; j < L; j += GRP){
    float2 pr = pairs[off + j];
    W[__float_as_uint(pr.y)] = expf(pr.x - m) * inv;
  }

  if (sl == 0){
    float b0=a0*inv, b1=a1*inv, b2=a2*inv, b3=a3*inv, b4=a4*inv, b5=a5*inv, b6=a6*inv;
    float b7=a7*inv, b8=a8*inv, b9=a9*inv;
    float r0=a10*inv, r1=a11*inv, r2=a12*inv, r3=a13*inv;
    float maxop = (L > 0u) ? mop : 0.0f;
    float nrm  = sqrtf(r0*r0 + r1*r1 + r2*r2 + r3*r3);
    float rinv = 1.0f / fmaxf(nrm, 1e-6f);
    float* f = F + (size_t)v * 15;
    f[0]=b0; f[1]=b1; f[2]=b2; f[3]=b3; f[4]=b4; f[5]=b5;
    f[6]=0.7f*maxop + 0.3f*b6;
    f[7]=expf(b7); f[8]=expf(b8); f[9]=expf(b9);
    f[10]=r0*rinv; f[11]=r1*rinv; f[12]=r2*rinv; f[13]=r3*rinv;
    f[14]=0.0f;
  }
}

extern "C" void kernel_launch(void* const* d_in, const int* in_sizes, int n_in,
                              void* d_out, int out_size, void* d_ws, size_t ws_size,
                              hipStream_t stream) {
  const float* feat = (const float*)d_in[0];
  const int*   vox  = (const int*)  d_in[1];
  const float* tt   = (const float*)d_in[3];
  const float* conf = (const float*)d_in[4];

  int N = in_sizes[0] / 15;
  int M = (out_size - N) / 15;
  int nb = (M + TPB - 1) / TPB;

  float* F = (float*)d_out;                      // fused gaussians: M*15
  float* W = (float*)d_out + (size_t)M * 15;     // weights: N

  unsigned* cnt  = (unsigned*)d_ws;              // M
  unsigned* cnt2 = cnt  + M;                     // M (rank pass)
  unsigned* offs = cnt2 + M;                     // M
  unsigned* bsum = offs + M;                     // nb
  size_t head = ((size_t)3 * M + nb + 63) & ~(size_t)63;   // 256B-align the payload
  float* body = (float*)d_ws + head;

  int gM = (M + TPB - 1) / TPB;
  int gN = (N + TPB - 1) / TPB;
  int gR = ((size_t)M * GRP + TPB - 1) / TPB;
  int gZ = (2 * M + TPB - 1) / TPB;

  k_zero <<<gZ, TPB, 0, stream>>>(cnt, 2 * M);   // cnt + cnt2
  k_count<<<gN, TPB, 0, stream>>>(vox, cnt, N);
  k_scan1<<<nb, TPB, 0, stream>>>(cnt, bsum, M);
  k_scan2<<<1,  TPB, 0, stream>>>(bsum, nb);
  k_scan3<<<nb, TPB, 0, stream>>>(cnt, bsum, offs, M);

  size_t needA = (head + (size_t)16 * N) * sizeof(float);
  if (ws_size >= needA){
    // PLAN A: 64B sorted payload, all-linear reduce
    k_transformA<<<gN, TPB, 0, stream>>>(feat, conf, vox, tt, offs, cnt2, body, N);
    k_reduceA  <<<gR, TPB, 0, stream>>>((const float4*)body, offs, cnt, F, W, M);
  } else {
    // PLAN B: 8B sorted (score,idx), single gather pass
    k_scoreB <<<gN, TPB, 0, stream>>>(feat, conf, vox, tt, offs, cnt2, (float2*)body, N);
    k_reduceB<<<gR, TPB, 0, stream>>>(feat, (const float2*)body, offs, cnt, F, W, M);
  }
}

// Round 4
// 599.258 us; speedup vs baseline: 6.1141x; 1.0387x over previous
//
#include <hip/hip_runtime.h>
#include <math.h>

#define TPB 256
#define GRP 16                        // lanes per voxel in reduce
#define EPSF 1e-6f
#define LOG_G1 -2.3025850929940457f   /* log(0.1) */
#define LOGEPS -13.815510557964274f   /* log(1e-6) */

// ---- 16-lane-group butterfly reductions (4 voxels per wave64) ----
__device__ __forceinline__ float gsum16(float x){
  #pragma unroll
  for (int k = 8; k >= 1; k >>= 1) x += __shfl_xor(x, k, 64);
  return x;
}
__device__ __forceinline__ float gmax16(float x){
  #pragma unroll
  for (int k = 8; k >= 1; k >>= 1) x = fmaxf(x, __shfl_xor(x, k, 64));
  return x;
}
__device__ __forceinline__ float score_from(float gt, float c, float t0){
  float g0 = fmaxf(c, EPSF);
  float dt = t0 - gt;
  // log(max(exp(sigma*dt^2),EPS))/T == max(sigma*dt^2, logEPS)/T exactly
  return fmaxf(LOG_G1 / (g0 * g0 + EPSF) * dt * dt, LOGEPS) / 0.07f;
}

// ---------------- zero counters ----------------
__global__ void k_zero(unsigned* __restrict__ p, int n){
  int i = blockIdx.x * TPB + threadIdx.x;
  if (i < n) p[i] = 0u;
}

// ---------------- histogram ----------------
__global__ void k_count(const int* __restrict__ vox, unsigned* __restrict__ cnt, int N){
  int i = blockIdx.x * TPB + threadIdx.x;
  if (i >= N) return;
  atomicAdd(&cnt[vox[i]], 1u);
}

// ---------------- scan: per-block sums ----------------
__global__ void k_scan1(const unsigned* __restrict__ cnt, unsigned* __restrict__ bsum, int M){
  __shared__ unsigned sm[TPB];
  int i = blockIdx.x * TPB + threadIdx.x;
  sm[threadIdx.x] = (i < M) ? cnt[i] : 0u;
  __syncthreads();
  for (int off = TPB / 2; off > 0; off >>= 1){
    if (threadIdx.x < off) sm[threadIdx.x] += sm[threadIdx.x + off];
    __syncthreads();
  }
  if (threadIdx.x == 0) bsum[blockIdx.x] = sm[0];
}

// ---------------- scan: exclusive scan of block sums (single block) ----------------
__global__ void k_scan2(unsigned* __restrict__ bsum, int nb){
  __shared__ unsigned sm[TPB];
  unsigned carry = 0;
  for (int base = 0; base < nb; base += TPB){
    int i = base + threadIdx.x;
    unsigned v = (i < nb) ? bsum[i] : 0u;
    sm[threadIdx.x] = v;
    __syncthreads();
    for (int off = 1; off < TPB; off <<= 1){
      unsigned t = (threadIdx.x >= off) ? sm[threadIdx.x - off] : 0u;
      __syncthreads();
      sm[threadIdx.x] += t;
      __syncthreads();
    }
    if (i < nb) bsum[i] = carry + sm[threadIdx.x] - v;   // exclusive
    carry += sm[TPB - 1];
    __syncthreads();
  }
}

// ---------------- scan: per-voxel exclusive offsets ----------------
__global__ void k_scan3(const unsigned* __restrict__ cnt, const unsigned* __restrict__ bsum,
                        unsigned* __restrict__ offs, int M){
  __shared__ unsigned sm[TPB];
  int i = blockIdx.x * TPB + threadIdx.x;
  unsigned v = (i < M) ? cnt[i] : 0u;
  sm[threadIdx.x] = v;
  __syncthreads();
  for (int off = 1; off < TPB; off <<= 1){
    unsigned t = (threadIdx.x >= off) ? sm[threadIdx.x - off] : 0u;
    __syncthreads();
    sm[threadIdx.x] += t;
    __syncthreads();
  }
  if (i < M) offs[i] = bsum[blockIdx.x] + sm[threadIdx.x] - v;
}

// ================= PLAN C: input-order payload (coalesced), sorted pairs =================
// payload row (16 floats, 64B aligned): [f0..f6, log(f7..f9), f10..f13, pad, pad]
__global__ __launch_bounds__(TPB)
void k_transform(const float* __restrict__ feat, const float* __restrict__ conf,
                 const int* __restrict__ vox, const float* __restrict__ tt,
                 const unsigned* __restrict__ offs, unsigned* __restrict__ cnt2,
                 float* __restrict__ payload, float2* __restrict__ pairs, int N){
  __shared__ float sf[TPB * 15];
  int base = blockIdx.x * TPB;
  int nrow = N - base; if (nrow > TPB) nrow = TPB;
  int nflt = nrow * 15;
  if (nflt == TPB * 15){
    const float4* g4 = (const float4*)(feat + (size_t)base * 15);
    float4* s4 = (float4*)sf;
    #pragma unroll
    for (int k = 0; k < 4; ++k){
      int j = threadIdx.x + k * TPB;
      if (j < TPB * 15 / 4) s4[j] = g4[j];
    }
  } else {
    for (int j = threadIdx.x; j < nflt; j += TPB)
      sf[j] = feat[(size_t)base * 15 + j];
  }
  __syncthreads();
  int t = threadIdx.x;
  float r[15]; float score = 0.f;
  bool hav = (t < nrow);
  if (hav){
    #pragma unroll
    for (int c = 0; c < 15; ++c) r[c] = sf[t * 15 + c];    // stride 15: conflict-free
    score = score_from(r[14], conf[base + t], tt[0]);
    r[7] = logf(fmaxf(r[7], 1e-6f));
    r[8] = logf(fmaxf(r[8], 1e-6f));
    r[9] = logf(fmaxf(r[9], 1e-6f));
  }
  __syncthreads();
  if (hav){
    #pragma unroll
    for (int c = 0; c < 14; ++c) sf[t * 15 + c] = r[c];    // transformed row back to LDS
  }
  __syncthreads();
  // cooperative, fully lane-coalesced payload write (16 floats/row)
  float4* pay4 = (float4*)(payload + (size_t)base * 16);
  int n4 = nrow * 4;
  for (int j = threadIdx.x; j < n4; j += TPB){
    int rr = j >> 2, q = j & 3;
    float4 o;
    if (q < 3) o = make_float4(sf[rr*15 + 4*q], sf[rr*15 + 4*q + 1],
                               sf[rr*15 + 4*q + 2], sf[rr*15 + 4*q + 3]);
    else       o = make_float4(sf[rr*15 + 12], sf[rr*15 + 13], 0.f, 0.f);
    pay4[j] = o;
  }
  // sorted (score, idx) pair: 8B scatter into L3-resident region
  if (hav){
    int i = base + t;
    int v = vox[i];
    unsigned rk = atomicAdd(&cnt2[v], 1u);
    pairs[offs[v] + rk] = make_float2(score, __uint_as_float((unsigned)i));
  }
}

__global__ __launch_bounds__(TPB)
void k_reduce(const float4* __restrict__ pay4, const float2* __restrict__ pairs,
              const unsigned* __restrict__ offs, const unsigned* __restrict__ cnt,
              float* __restrict__ F, float* __restrict__ W, int M){
  int v = blockIdx.x * (TPB / GRP) + (int)(threadIdx.x / GRP);
  if (v >= M) return;
  int sl = threadIdx.x & (GRP - 1);
  unsigned off = offs[v], L = cnt[v];

  // phase 0: max over sorted scores (linear)
  float m = -INFINITY;
  for (unsigned j = sl; j < L; j += GRP)
    m = fmaxf(m, pairs[off + j].x);
  m = gmax16(m);

  // phase 1: single-line gathers of input-order payload
  float se = 0.f, mop = -INFINITY;
  float a0=0,a1=0,a2=0,a3=0,a4=0,a5=0,a6=0,a7=0,a8=0,a9=0,a10=0,a11=0,a12=0,a13=0;
  for (unsigned j = sl; j < L; j += GRP){
    float2 pr = pairs[off + j];                       // L2/L3-hot
    size_t b  = (size_t)__float_as_uint(pr.y) * 4;
    float4 q0 = pay4[b], q1 = pay4[b+1], q2 = pay4[b+2], q3 = pay4[b+3];
    float e = expf(pr.x - m);
    se += e;
    mop = fmaxf(mop, q1.z);
    a0 += q0.x*e; a1 += q0.y*e; a2  += q0.z*e; a3  += q0.w*e;
    a4 += q1.x*e; a5 += q1.y*e; a6  += q1.z*e; a7  += q1.w*e;
    a8 += q2.x*e; a9 += q2.y*e; a10 += q2.z*e; a11 += q2.w*e;
    a12 += q3.x*e; a13 += q3.y*e;
  }
  se  = gsum16(se);
  a0  = gsum16(a0);  a1  = gsum16(a1);  a2  = gsum16(a2);  a3  = gsum16(a3);
  a4  = gsum16(a4);  a5  = gsum16(a5);  a6  = gsum16(a6);  a7  = gsum16(a7);
  a8  = gsum16(a8);  a9  = gsum16(a9);  a10 = gsum16(a10); a11 = gsum16(a11);
  a12 = gsum16(a12); a13 = gsum16(a13);
  mop = gmax16(mop);

  float inv = (L > 0u) ? 1.0f / se : 0.0f;

  // phase 2: per-gaussian weights (pairs L1-hot, 4B scatter into 17MB region)
  for (unsigned j = sl; j < L; j += GRP){
    float2 pr = pairs[off + j];
    W[__float_as_uint(pr.y)] = expf(pr.x - m) * inv;
  }

  if (sl == 0){
    float b0=a0*inv, b1=a1*inv, b2=a2*inv, b3=a3*inv, b4=a4*inv, b5=a5*inv, b6=a6*inv;
    float b7=a7*inv, b8=a8*inv, b9=a9*inv;
    float r0=a10*inv, r1=a11*inv, r2=a12*inv, r3=a13*inv;
    float maxop = (L > 0u) ? mop : 0.0f;
    float nrm  = sqrtf(r0*r0 + r1*r1 + r2*r2 + r3*r3);
    float rinv = 1.0f / fmaxf(nrm, 1e-6f);
    float* f = F + (size_t)v * 15;
    f[0]=b0; f[1]=b1; f[2]=b2; f[3]=b3; f[4]=b4; f[5]=b5;
    f[6]=0.7f*maxop + 0.3f*b6;
    f[7]=expf(b7); f[8]=expf(b8); f[9]=expf(b9);
    f[10]=r0*rinv; f[11]=r1*rinv; f[12]=r2*rinv; f[13]=r3*rinv;
    f[14]=0.0f;
  }
}

// ================= PLAN A fallback (R3): sorted 64B payload scatter =================
__global__ __launch_bounds__(TPB)
void k_transformA(const float* __restrict__ feat, const float* __restrict__ conf,
                  const int* __restrict__ vox, const float* __restrict__ tt,
                  const unsigned* __restrict__ offs, unsigned* __restrict__ cnt2,
                  float* __restrict__ payload, int N){
  __shared__ float sf[TPB * 15];
  int base = blockIdx.x * TPB;
  int nrow = N - base; if (nrow > TPB) nrow = TPB;
  int nflt = nrow * 15;
  if (nflt == TPB * 15){
    const float4* g4 = (const float4*)(feat + (size_t)base * 15);
    float4* s4 = (float4*)sf;
    #pragma unroll
    for (int k = 0; k < 4; ++k){
      int idx = threadIdx.x + k * TPB;
      if (idx < TPB * 15 / 4) s4[idx] = g4[idx];
    }
  } else {
    for (int idx = threadIdx.x; idx < nflt; idx += TPB)
      sf[idx] = feat[(size_t)base * 15 + idx];
  }
  __syncthreads();
  int t = threadIdx.x;
  if (t >= nrow) return;
  int i = base + t;
  const float* r = &sf[t * 15];
  float s  = score_from(r[14], conf[i], tt[0]);
  int   v  = vox[i];
  unsigned rk = atomicAdd(&cnt2[v], 1u);
  size_t pos = (size_t)(offs[v] + rk) * 16;
  float4* p4 = (float4*)(payload + pos);
  p4[0] = make_float4(r[0], r[1], r[2], r[3]);
  p4[1] = make_float4(r[4], r[5], r[6], logf(fmaxf(r[7], 1e-6f)));
  p4[2] = make_float4(logf(fmaxf(r[8], 1e-6f)), logf(fmaxf(r[9], 1e-6f)), r[10], r[11]);
  p4[3] = make_float4(r[12], r[13], s, __uint_as_float((unsigned)i));
}

__global__ __launch_bounds__(TPB)
void k_reduceA(const float4* __restrict__ pay4, const unsigned* __restrict__ offs,
               const unsigned* __restrict__ cnt, float* __restrict__ F,
               float* __restrict__ W, int M){
  int v = blockIdx.x * (TPB / GRP) + (int)(threadIdx.x / GRP);
  if (v >= M) return;
  int sl = threadIdx.x & (GRP - 1);
  unsigned off = offs[v], L = cnt[v];
  float m = -INFINITY;
  for (unsigned j = sl; j < L; j += GRP)
    m = fmaxf(m, pay4[(size_t)(off + j) * 4 + 3].z);
  m = gmax16(m);
  float se = 0.f, mop = -INFINITY;
  float a0=0,a1=0,a2=0,a3=0,a4=0,a5=0,a6=0,a7=0,a8=0,a9=0,a10=0,a11=0,a12=0,a13=0;
  for (unsigned j = sl; j < L; j += GRP){
    size_t b = (size_t)(off + j) * 4;
    float4 q0 = pay4[b], q1 = pay4[b+1], q2 = pay4[b+2], q3 = pay4[b+3];
    float e = expf(q3.z - m);
    se += e;
    mop = fmaxf(mop, q1.z);
    a0 += q0.x*e; a1 += q0.y*e; a2  += q0.z*e; a3  += q0.w*e;
    a4 += q1.x*e; a5 += q1.y*e; a6  += q1.z*e; a7  += q1.w*e;
    a8 += q2.x*e; a9 += q2.y*e; a10 += q2.z*e; a11 += q2.w*e;
    a12 += q3.x*e; a13 += q3.y*e;
  }
  se  = gsum16(se);
  a0  = gsum16(a0);  a1  = gsum16(a1);  a2  = gsum16(a2);  a3  = gsum16(a3);
  a4  = gsum16(a4);  a5  = gsum16(a5);  a6  = gsum16(a6);  a7  = gsum16(a7);
  a8  = gsum16(a8);  a9  = gsum16(a9);  a10 = gsum16(a10); a11 = gsum16(a11);
  a12 = gsum16(a12); a13 = gsum16(a13);
  mop = gmax16(mop);
  float inv = (L > 0u) ? 1.0f / se : 0.0f;
  for (unsigned j = sl; j < L; j += GRP){
    float4 q3 = pay4[(size_t)(off + j) * 4 + 3];
    W[__float_as_uint(q3.w)] = expf(q3.z - m) * inv;
  }
  if (sl == 0){
    float b0=a0*inv, b1=a1*inv, b2=a2*inv, b3=a3*inv, b4=a4*inv, b5=a5*inv, b6=a6*inv;
    float b7=a7*inv, b8=a8*inv, b9=a9*inv;
    float r0=a10*inv, r1=a11*inv, r2=a12*inv, r3=a13*inv;
    float maxop = (L > 0u) ? mop : 0.0f;
    float nrm  = sqrtf(r0*r0 + r1*r1 + r2*r2 + r3*r3);
    float rinv = 1.0f / fmaxf(nrm, 1e-6f);
    float* f = F + (size_t)v * 15;
    f[0]=b0; f[1]=b1; f[2]=b2; f[3]=b3; f[4]=b4; f[5]=b5;
    f[6]=0.7f*maxop + 0.3f*b6;
    f[7]=expf(b7); f[8]=expf(b8); f[9]=expf(b9);
    f[10]=r0*rinv; f[11]=r1*rinv; f[12]=r2*rinv; f[13]=r3*rinv;
    f[14]=0.0f;
  }
}

extern "C" void kernel_launch(void* const* d_in, const int* in_sizes, int n_in,
                              void* d_out, int out_size, void* d_ws, size_t ws_size,
                              hipStream_t stream) {
  const float* feat = (const float*)d_in[0];
  const int*   vox  = (const int*)  d_in[1];
  const float* tt   = (const float*)d_in[3];
  const float* conf = (const float*)d_in[4];

  int N = in_sizes[0] / 15;
  int M = (out_size - N) / 15;
  int nb = (M + TPB - 1) / TPB;

  float* F = (float*)d_out;                      // fused gaussians: M*15
  float* W = (float*)d_out + (size_t)M * 15;     // weights: N

  unsigned* cnt  = (unsigned*)d_ws;              // M
  unsigned* cnt2 = cnt  + M;                     // M (rank pass)
  unsigned* offs = cnt2 + M;                     // M
  unsigned* bsum = offs + M;                     // nb
  size_t head = ((size_t)3 * M + nb + 63) & ~(size_t)63;   // 256B-align the payload
  float*  body  = (float*)d_ws + head;           // payload: 16N floats
  float2* pairs = (float2*)(body + (size_t)16 * N);        // 2N floats

  int gM = (M + TPB - 1) / TPB;
  int gN = (N + TPB - 1) / TPB;
  int gR = ((size_t)M * GRP + TPB - 1) / TPB;
  int gZ = (2 * M + TPB - 1) / TPB;

  k_zero <<<gZ, TPB, 0, stream>>>(cnt, 2 * M);   // cnt + cnt2
  k_count<<<gN, TPB, 0, stream>>>(vox, cnt, N);
  k_scan1<<<nb, TPB, 0, stream>>>(cnt, bsum, M);
  k_scan2<<<1,  TPB, 0, stream>>>(bsum, nb);
  k_scan3<<<nb, TPB, 0, stream>>>(cnt, bsum, offs, M);

  size_t needC = (head + (size_t)18 * N) * sizeof(float);
  size_t needA = (head + (size_t)16 * N) * sizeof(float);
  if (ws_size >= needC){
    // PLAN C: input-order payload (coalesced write) + sorted pairs, line-gather reduce
    k_transform<<<gN, TPB, 0, stream>>>(feat, conf, vox, tt, offs, cnt2, body, pairs, N);
    k_reduce   <<<gR, TPB, 0, stream>>>((const float4*)body, pairs, offs, cnt, F, W, M);
  } else if (ws_size >= needA){
    // PLAN A: sorted 64B payload scatter (R3 path)
    k_transformA<<<gN, TPB, 0, stream>>>(feat, conf, vox, tt, offs, cnt2, body, N);
    k_reduceA   <<<gR, TPB, 0, stream>>>((const float4*)body, offs, cnt, F, W, M);
  }
}